// Round 1
// 658.735 us; speedup vs baseline: 1.0633x; 1.0633x over previous
//
#include <hip/hip_runtime.h>

// Problem shape (fixed by the reference): x[B,D] fp32, L[V,D] fp32,
// target[B] int, class_weight[V] fp32 -> scalar fp32 loss.
#define B_ 4096
#define D_ 2048
#define V_ 32000

// R7: 256x256 tile, 8 waves (2M x 4N), double-buffered LDS, phased schedule.
// Rationale: at 128x128/4-wave the LDS read bytes per MFMA FLOP sit exactly at
// the 128 B/cy LDS ceiling -> MfmaUtil capped ~32%. At 256x256/8-wave each
// operand byte is read once per wave: 192KB reads + 64KB writes per K-tile
// (~2000 cy) vs 2212 cy of MFMA -> compute-bound with headroom.
#define BM 256
#define BN 256
#define BKB 128              // K-tile depth in BYTES (fp8: 128 elements)
#define NT (D_ / BKB)        // 16 K-tiles
#define NCHUNK (V_ / 64)     // 500 per-row (max,sumexp) partials, one per 64-col wave tile

typedef __attribute__((ext_vector_type(8))) int   int8v;   // 8 dwords = fp8 A/B frag
typedef __attribute__((ext_vector_type(4))) int   int4v;
typedef __attribute__((ext_vector_type(4))) float f32x4;

// e8m0 scales: value = 2^(byte-127). x quantized as-is -> scale 2^0 = 127.
// L quantized as L*2^6 (lifts ~0.02-magnitude entries out of e4m3 subnormal
// range) -> scale 2^-6 = 121. Uniform scales => scale-lane mapping irrelevant.
#define SCALE_A 127
#define SCALE_B 121

// ---------------------------------------------------------------- helpers ---
__device__ __forceinline__ void load_lds16(const void* g, void* l) {
    // async global->LDS, 16B per lane; LDS dest must be wave-uniform base + lane*16
    __builtin_amdgcn_global_load_lds(
        (const __attribute__((address_space(1))) void*)g,
        (__attribute__((address_space(3))) void*)l,
        16, 0, 0);
}

// ------------------------------------------------------------ cast kernel ---
// Fused x + L cast, 4 floats -> 4 fp8 bytes per thread. Fully contiguous:
// 16B/lane float4 reads, 4B/lane dword writes. (Unchanged this round to
// isolate the gemm restructure.)
__global__ void cast_f32_to_fp8(const float* __restrict__ x,
                                const float* __restrict__ L,
                                unsigned int* __restrict__ xq,
                                unsigned int* __restrict__ Lq) {
    const int n4x = (B_ * D_) / 4;
    const int n4l = (V_ * D_) / 4;
    int i = blockIdx.x * blockDim.x + threadIdx.x;
    const float* in; unsigned int* out; float ps; int j;
    if (i < n4x) { in = x; out = xq; ps = 1.0f;  j = i; }
    else         { j = i - n4x; if (j >= n4l) return; in = L; out = Lq; ps = 64.0f; }
    float4 v = ((const float4*)in)[j];
    int w = __builtin_amdgcn_cvt_pk_fp8_f32(v.x * ps, v.y * ps, 0, false);
    w     = __builtin_amdgcn_cvt_pk_fp8_f32(v.z * ps, v.w * ps, w, true);
    out[j] = (unsigned)w;
}

// ------------------------------------------------- GEMM + online-softmax ----
// grid (B/BM=16 FAST, V/BN=125 SLOW): in-flight 256 blocks = 16 row x 16 col
// blocks -> L2-friendly.
//
// MX-fp8 path: mfma_scale_f32_16x16x128_f8f6f4 (K=128/instr). Uniform e8m0
// scales => any k-permutation applied IDENTICALLY to A and B fragments is
// invisible to the math. Chunk map c(quad,h) = quad + 4h makes fragment reads
// hit LDS positions (quad^swz), ((quad+4)^swz) -- measured 0 bank conflicts.
// C layout = standard 16x16 (col=lane&15, row=quad*4+reg; dtype-independent).
//
// LDS: XOR-swizzled 16B chunks (8 chunks/row of 128B). Row r stores global
// chunk c at position c^(r&7), via pre-swizzled global source addresses
// (global_load_lds destination must stay linear lane*16).
//
// Schedule (T3+T4+T5): per K-tile, 4 phases of
//   {ds_read frag subtile | issue prefetch -> s_barrier -> setprio(1) ->
//    8 MFMA -> setprio(0) -> s_barrier}
// Raw s_barrier only (NO __syncthreads -> no forced vmcnt(0) drain).
// The 8 global_load_lds passes for tile t+1 are issued in phases 1-2 of
// tile t (>= ~1100 cy of MFMA cover); a single s_waitcnt vmcnt(0) sits just
// before the tile-boundary barrier (phase 4), so in steady state the drain
// costs ~nothing while loads overlap the whole tile's compute.
__global__ __launch_bounds__(512, 2)
void gemm_ce_partials(const unsigned char* __restrict__ xq,   // [B_,D_] fp8
                      const unsigned char* __restrict__ Lq,   // [V_,D_] fp8 (x2^6)
                      const int* __restrict__ targ,           // [B_]
                      float2* __restrict__ partials,          // [B_][NCHUNK]
                      float* __restrict__ gathered) {         // [B_] logit@target
    __shared__ __align__(16) unsigned char As[2][BM * BKB];   // 2 x 32 KB
    __shared__ __align__(16) unsigned char Bs[2][BN * BKB];   // 2 x 32 KB

    const int tid    = threadIdx.x;
    const int lane   = tid & 63;
    const int wid    = tid >> 6;         // 0..7
    const int wave_m = wid >> 2;         // 0..1  (row half: 128 rows)
    const int wave_n = wid & 3;          // 0..3  (col quarter: 64 cols)
    const int quad   = lane >> 4;        // 0..3
    const int l16    = lane & 15;
    const int swz    = l16 & 7;          // read-side XOR key (row&7 == l16&7)

    const int m0 = blockIdx.x * BM;      // row-block: FAST dim
    const int n0 = blockIdx.y * BN;      // col-block: SLOW dim

    // per-thread staging geometry: 4 passes x (1 A + 1 B) global_load_lds.
    // flat chunk id f = p*512+tid in [0,2048): row=f>>3, LDS pos pc=f&7,
    // global chunk c = pc ^ (row&7)  (XOR involution -> linear LDS dest).
    const unsigned char* srcA[4];
    const unsigned char* srcB[4];
    int dstoff[4];
#pragma unroll
    for (int p = 0; p < 4; ++p) {
        int flat = p * 512 + tid;
        int row  = flat >> 3;
        int pc   = flat & 7;
        int c    = pc ^ (row & 7);
        dstoff[p] = flat * 16;
        srcA[p] = xq + (size_t)(m0 + row) * D_ + c * 16;
        srcB[p] = Lq + (size_t)(n0 + row) * D_ + c * 16;
    }

    f32x4 acc[8][4];
#pragma unroll
    for (int i = 0; i < 8; ++i)
#pragma unroll
        for (int j = 0; j < 4; ++j)
            acc[i][j] = (f32x4){0.f, 0.f, 0.f, 0.f};

    // byte offsets of this lane's two 16B pieces (chunks quad and quad+4,
    // XOR-swizzled): the measured-zero-conflict read phases.
    const int p0 = ((quad ^ swz) << 4);
    const int p1 = p0 ^ 64;              // ((quad+4)^swz)<<4

    // ---- prologue: stage K-tile 0 into buffer 0, full drain once ----------
#pragma unroll
    for (int p = 0; p < 4; ++p) {
        load_lds16(srcA[p], &As[0][dstoff[p]]);
        load_lds16(srcB[p], &Bs[0][dstoff[p]]);
    }
    asm volatile("s_waitcnt vmcnt(0)" ::: "memory");
    __builtin_amdgcn_s_barrier();

    for (int kt = 0; kt < NT; ++kt) {
        const int cur = kt & 1;
        const int nxt = cur ^ 1;
        const int k1  = (kt + 1) * BKB;      // prefetch k-offset
        const bool pf = (kt + 1 < NT);

        int8v a[4], b[4];

        // ===== phase 1: read a(mi 0-3) + b(ni 0-1); issue A prefetch =======
#pragma unroll
        for (int mi = 0; mi < 4; ++mi) {
            int base = (wave_m * 128 + mi * 16 + l16) * BKB;
            union { int8v v8; int4v v4[2]; } u;
            u.v4[0] = *(const int4v*)&As[cur][base + p0];
            u.v4[1] = *(const int4v*)&As[cur][base + p1];
            a[mi] = u.v8;
        }
#pragma unroll
        for (int ni = 0; ni < 2; ++ni) {
            int base = (wave_n * 64 + ni * 16 + l16) * BKB;
            union { int8v v8; int4v v4[2]; } u;
            u.v4[0] = *(const int4v*)&Bs[cur][base + p0];
            u.v4[1] = *(const int4v*)&Bs[cur][base + p1];
            b[ni] = u.v8;
        }
        if (pf) {
#pragma unroll
            for (int p = 0; p < 4; ++p)
                load_lds16(srcA[p] + k1, &As[nxt][dstoff[p]]);
        }
        __builtin_amdgcn_s_barrier();
        __builtin_amdgcn_s_setprio(1);
#pragma unroll
        for (int mi = 0; mi < 4; ++mi)
#pragma unroll
            for (int ni = 0; ni < 2; ++ni)
                acc[mi][ni] = __builtin_amdgcn_mfma_scale_f32_16x16x128_f8f6f4(
                    a[mi], b[ni], acc[mi][ni], 0, 0, 0, SCALE_A, 0, SCALE_B);
        __builtin_amdgcn_s_setprio(0);
        __builtin_amdgcn_s_barrier();

        // ===== phase 2: read b(ni 2-3); issue B prefetch ===================
#pragma unroll
        for (int ni = 2; ni < 4; ++ni) {
            int base = (wave_n * 64 + ni * 16 + l16) * BKB;
            union { int8v v8; int4v v4[2]; } u;
            u.v4[0] = *(const int4v*)&Bs[cur][base + p0];
            u.v4[1] = *(const int4v*)&Bs[cur][base + p1];
            b[ni] = u.v8;
        }
        if (pf) {
#pragma unroll
            for (int p = 0; p < 4; ++p)
                load_lds16(srcB[p] + k1, &Bs[nxt][dstoff[p]]);
        }
        __builtin_amdgcn_s_barrier();
        __builtin_amdgcn_s_setprio(1);
#pragma unroll
        for (int mi = 0; mi < 4; ++mi)
#pragma unroll
            for (int ni = 2; ni < 4; ++ni)
                acc[mi][ni] = __builtin_amdgcn_mfma_scale_f32_16x16x128_f8f6f4(
                    a[mi], b[ni], acc[mi][ni], 0, 0, 0, SCALE_A, 0, SCALE_B);
        __builtin_amdgcn_s_setprio(0);
        __builtin_amdgcn_s_barrier();

        // ===== phase 3: read a(mi 4-7) over a[0..3] ========================
#pragma unroll
        for (int mi = 0; mi < 4; ++mi) {
            int base = (wave_m * 128 + (mi + 4) * 16 + l16) * BKB;
            union { int8v v8; int4v v4[2]; } u;
            u.v4[0] = *(const int4v*)&As[cur][base + p0];
            u.v4[1] = *(const int4v*)&As[cur][base + p1];
            a[mi] = u.v8;
        }
        __builtin_amdgcn_s_barrier();
        __builtin_amdgcn_s_setprio(1);
#pragma unroll
        for (int mi = 0; mi < 4; ++mi)
#pragma unroll
            for (int ni = 0; ni < 2; ++ni)
                acc[mi + 4][ni] = __builtin_amdgcn_mfma_scale_f32_16x16x128_f8f6f4(
                    a[mi], b[ni], acc[mi + 4][ni], 0, 0, 0, SCALE_A, 0, SCALE_B);
        __builtin_amdgcn_s_setprio(0);
        __builtin_amdgcn_s_barrier();

        // ===== phase 4: remaining quadrant; single per-tile vmcnt drain ====
        __builtin_amdgcn_s_setprio(1);
#pragma unroll
        for (int mi = 0; mi < 4; ++mi)
#pragma unroll
            for (int ni = 2; ni < 4; ++ni)
                acc[mi + 4][ni] = __builtin_amdgcn_mfma_scale_f32_16x16x128_f8f6f4(
                    a[mi], b[ni], acc[mi + 4][ni], 0, 0, 0, SCALE_A, 0, SCALE_B);
        __builtin_amdgcn_s_setprio(0);
        asm volatile("s_waitcnt vmcnt(0)" ::: "memory");
        __builtin_amdgcn_s_barrier();
    }

    // Epilogue. C layout (16x16): col = lane&15, row = quad*4 + reg.
    // Per wave: 128 rows (wave_m half, mi 0..7) x 64 cols (wave_n quarter).
    const int row_base = m0 + wave_m * 128;
    const int col_base = n0 + wave_n * 64;
    const int chunk    = blockIdx.y * 4 + wave_n;   // 0..499

    // hoist targ loads (latency overlaps the max/exp work below)
    int tv[32];
#pragma unroll
    for (int mi = 0; mi < 8; ++mi)
#pragma unroll
        for (int r = 0; r < 4; ++r)
            tv[mi * 4 + r] = targ[row_base + mi * 16 + quad * 4 + r];

    // wave-wide max M (valid shift for all 128 rows of this wave tile)
    float M = acc[0][0][0];
#pragma unroll
    for (int mi = 0; mi < 8; ++mi)
#pragma unroll
        for (int ni = 0; ni < 4; ++ni)
#pragma unroll
            for (int r = 0; r < 4; ++r)
                M = fmaxf(M, acc[mi][ni][r]);
#pragma unroll
    for (int off = 1; off < 64; off <<= 1)
        M = fmaxf(M, __shfl_xor(M, off, 64));

    // all exps first (independent), then flat shuffle rounds (32-way ILP)
    float sv[32];
#pragma unroll
    for (int mi = 0; mi < 8; ++mi)
#pragma unroll
        for (int r = 0; r < 4; ++r)
            sv[mi * 4 + r] = __expf(acc[mi][0][r] - M) + __expf(acc[mi][1][r] - M) +
                             __expf(acc[mi][2][r] - M) + __expf(acc[mi][3][r] - M);
#pragma unroll
    for (int off = 1; off < 16; off <<= 1)
#pragma unroll
        for (int i = 0; i < 32; ++i)
            sv[i] += __shfl_xor(sv[i], off, 64);

    if (l16 == 0) {
#pragma unroll
        for (int mi = 0; mi < 8; ++mi)
#pragma unroll
            for (int r = 0; r < 4; ++r) {
                int row = row_base + mi * 16 + quad * 4 + r;
                partials[(size_t)row * NCHUNK + chunk] = make_float2(M, sv[mi * 4 + r]);
            }
    }

    // target gather (rare hit: ~4096/32000 of (row, col-block) pairs)
#pragma unroll
    for (int mi = 0; mi < 8; ++mi)
#pragma unroll
        for (int r = 0; r < 4; ++r) {
            int row = row_base + mi * 16 + quad * 4 + r;
            int cb  = col_base + l16;
            int t   = tv[mi * 4 + r];
            if (cb      == t) gathered[row] = acc[mi][0][r];
            if (cb + 16 == t) gathered[row] = acc[mi][1][r];
            if (cb + 32 == t) gathered[row] = acc[mi][2][r];
            if (cb + 48 == t) gathered[row] = acc[mi][3][r];
        }
}

// ------------------------------------------------------ per-row combine -----
// one wave per row; block 256 -> 4 rows/block; grid B_/4
__global__ void combine_rows(const float2* __restrict__ partials,
                             const float* __restrict__ gathered,
                             const int* __restrict__ targ,
                             const float* __restrict__ cw,
                             float* __restrict__ row_loss,
                             float* __restrict__ row_w) {
    int row  = blockIdx.x * 4 + (threadIdx.x >> 6);
    int lane = threadIdx.x & 63;
    float m = -3.0e38f, s = 0.f;
    for (int c = lane; c < NCHUNK; c += 64) {
        float2 p = partials[(size_t)row * NCHUNK + c];
        float nm = fmaxf(m, p.x);
        s = s * __expf(m - nm) + p.y * __expf(p.x - nm);
        m = nm;
    }
#pragma unroll
    for (int off = 32; off; off >>= 1) {
        float om = __shfl_xor(m, off, 64);
        float os = __shfl_xor(s, off, 64);
        float nm = fmaxf(m, om);
        s = s * __expf(m - nm) + os * __expf(om - nm);
        m = nm;
    }
    if (lane == 0) {
        float logZ = m + __logf(s);
        int t = targ[row];
        bool valid = (t != -100);
        int ts = valid ? t : 0;
        float w = valid ? cw[ts] : 0.f;
        row_loss[row] = w * (logZ - gathered[row]);
        row_w[row]    = w;
    }
}

// ---------------------------------------------------------- final reduce ----
__global__ void final_reduce(const float* __restrict__ rl,
                             const float* __restrict__ rw,
                             float* __restrict__ out) {
    __shared__ float sl[4], sw[4];
    float a = 0.f, b = 0.f;
    for (int i = threadIdx.x; i < B_; i += 256) { a += rl[i]; b += rw[i]; }
#pragma unroll
    for (int off = 32; off; off >>= 1) {
        a += __shfl_xor(a, off, 64);
        b += __shfl_xor(b, off, 64);
    }
    int w = threadIdx.x >> 6;
    if ((threadIdx.x & 63) == 0) { sl[w] = a; sw[w] = b; }
    __syncthreads();
    if (threadIdx.x == 0) {
        float ta = sl[0] + sl[1] + sl[2] + sl[3];
        float tb = sw[0] + sw[1] + sw[2] + sw[3];
        out[0] = ta / tb;
    }
}

// ------------------------------------------------------------------ launch --
extern "C" void kernel_launch(void* const* d_in, const int* in_sizes, int n_in,
                              void* d_out, int out_size, void* d_ws, size_t ws_size,
                              hipStream_t stream) {
    const float* x  = (const float*)d_in[0];   // [B_,D_]
    const float* L  = (const float*)d_in[1];   // [V_,D_]
    const int* targ = (const int*)d_in[2];     // [B_]
    const float* cw = (const float*)d_in[3];   // [V_]
    float* out = (float*)d_out;

    // workspace carve-up (all 256B-aligned)
    char* ws = (char*)d_ws;
    size_t o = 0;
    unsigned char* xq = (unsigned char*)(ws + o);  o += (size_t)B_ * D_;         // 8.4 MB
    unsigned char* Lq = (unsigned char*)(ws + o);  o += (size_t)V_ * D_;         // 65.5 MB
    float2* partials = (float2*)(ws + o);          o += (size_t)B_ * NCHUNK * 8; // 16.4 MB
    float* gathered = (float*)(ws + o);            o += (size_t)B_ * 4;
    float* row_loss = (float*)(ws + o);            o += (size_t)B_ * 4;
    float* row_w    = (float*)(ws + o);            o += (size_t)B_ * 4;
    (void)ws_size;

    // 1) fused cast (x as-is; L pre-scaled 2^6, undone by MFMA e8m0 scale 2^-6)
    {
        int n4 = (B_ * D_) / 4 + (V_ * D_) / 4;
        cast_f32_to_fp8<<<(n4 + 255) / 256, 256, 0, stream>>>(
            x, L, (unsigned*)xq, (unsigned*)Lq);
    }

    // 2) fused MX-fp8 GEMM + per-tile online softmax partials
    {
        dim3 grid(B_ / BM, V_ / BN);   // (16 fast, 125 slow) -- L2 locality
        gemm_ce_partials<<<grid, 512, 0, stream>>>(xq, Lq, targ, partials, gathered);
    }

    // 3) per-row combine
    combine_rows<<<B_ / 4, 256, 0, stream>>>(partials, gathered, targ, cw, row_loss, row_w);

    // 4) final scalar
    final_reduce<<<1, 256, 0, stream>>>(row_loss, row_w, out);
}

// Round 2
// 650.176 us; speedup vs baseline: 1.0773x; 1.0132x over previous
//
#include <hip/hip_runtime.h>

// Problem shape (fixed by the reference): x[B,D] fp32, L[V,D] fp32,
// target[B] int, class_weight[V] fp32 -> scalar fp32 loss.
#define B_ 4096
#define D_ 2048
#define V_ 32000

// R8: 256x256 / 8-wave / double-buffered LDS, READ-BALANCED + PIPELINED phases.
// R7 post-mortem: MfmaUtil 37% == the fully-serialized model (LDS 2300cy + MFMA
// 2212cy per tile, zero overlap). Cause: phase read counts 12/4/8/0 -- the
// read-free phase 4 re-aligns all waves, phase 1 then drains 96 CU-reads with
// the MFMA pipe idle. Fix: issue each phase's frag reads ONE PHASE EARLY so
// the compiler's per-operand lgkmcnt lets MFMA_p overlap reads_{p+1}; every
// barrier has read work queued; post-MFMA barriers dropped (intra-tile the
// frag buffer is read-only, stage targets the other buffer).
#define BM 256
#define BN 256
#define BKB 128              // K-tile depth in BYTES (fp8: 128 elements)
#define NT (D_ / BKB)        // 16 K-tiles
#define NCHUNK (V_ / 64)     // 500 per-row (max,sumexp) partials, one per 64-col wave tile

typedef __attribute__((ext_vector_type(8))) int   int8v;   // 8 dwords = fp8 A/B frag
typedef __attribute__((ext_vector_type(4))) int   int4v;
typedef __attribute__((ext_vector_type(4))) float f32x4;

// e8m0 scales: value = 2^(byte-127). x quantized as-is -> scale 2^0 = 127.
// L quantized as L*2^6 (lifts ~0.02-magnitude entries out of e4m3 subnormal
// range) -> scale 2^-6 = 121. Uniform scales => scale-lane mapping irrelevant.
#define SCALE_A 127
#define SCALE_B 121

// ---------------------------------------------------------------- helpers ---
__device__ __forceinline__ void load_lds16(const void* g, void* l) {
    // async global->LDS, 16B per lane; LDS dest must be wave-uniform base + lane*16
    __builtin_amdgcn_global_load_lds(
        (const __attribute__((address_space(1))) void*)g,
        (__attribute__((address_space(3))) void*)l,
        16, 0, 0);
}

__device__ __forceinline__ int8v frag(const unsigned char* buf, int base, int p0, int p1) {
    union { int8v v8; int4v v4[2]; } u;
    u.v4[0] = *(const int4v*)(buf + base + p0);
    u.v4[1] = *(const int4v*)(buf + base + p1);
    return u.v8;
}

// ------------------------------------------------------------ cast kernel ---
// Fused x + L cast, 4 floats -> 4 fp8 bytes per thread. Fully contiguous:
// 16B/lane float4 reads, 4B/lane dword writes.
__global__ void cast_f32_to_fp8(const float* __restrict__ x,
                                const float* __restrict__ L,
                                unsigned int* __restrict__ xq,
                                unsigned int* __restrict__ Lq) {
    const int n4x = (B_ * D_) / 4;
    const int n4l = (V_ * D_) / 4;
    int i = blockIdx.x * blockDim.x + threadIdx.x;
    const float* in; unsigned int* out; float ps; int j;
    if (i < n4x) { in = x; out = xq; ps = 1.0f;  j = i; }
    else         { j = i - n4x; if (j >= n4l) return; in = L; out = Lq; ps = 64.0f; }
    float4 v = ((const float4*)in)[j];
    int w = __builtin_amdgcn_cvt_pk_fp8_f32(v.x * ps, v.y * ps, 0, false);
    w     = __builtin_amdgcn_cvt_pk_fp8_f32(v.z * ps, v.w * ps, w, true);
    out[j] = (unsigned)w;
}

// ------------------------------------------------- GEMM + online-softmax ----
// MX-fp8 path: mfma_scale_f32_16x16x128_f8f6f4 (K=128/instr). Uniform e8m0
// scales => any k-permutation applied IDENTICALLY to A and B fragments is
// invisible to the math. Chunk map c(quad,h) = quad + 4h makes fragment reads
// hit LDS positions (quad^swz), ((quad+4)^swz) -- measured 0 bank conflicts.
// C layout = standard 16x16 (col=lane&15, row=quad*4+reg; dtype-independent).
//
// LDS: XOR-swizzled 16B chunks (8 chunks/row of 128B). Row r stores global
// chunk c at position c^(r&7), via pre-swizzled global source addresses
// (global_load_lds destination must stay linear lane*16).
//
// Per-tile schedule (reads pipelined one phase ahead of use; 5 barriers):
//  P1: rd{a0,a1,b0, a2,a3,b1}(12) | stage B-h1 | BAR | mm{a0b0,a1b0}(2)
//  P2: rd{b2,b3,s=A4}(6)          | stage B-h2 | BAR | mm{a2-3·b0, a0-3·b1}(6)
//  P3:                              stage A-h1 | BAR | mm{a0-3·b2, a0-3·b3}(8)
//  P4: rd{a0=A5,a1=A6,a2=A7}(6)   | stage A-h2 | BAR | mm{s·b*, A5-7·b*}(16)
//      s_waitcnt vmcnt(0); BAR    (boundary: buffer swap)
// mm_p never waits on same-phase reads except P1's first 6 and P4's reload
// (whose drain hides under the 4 s·b* MFMAs issued first). Stage order B
// before A: B is the HBM-miss-prone operand, A is L2-hot by round 2.
__global__ __launch_bounds__(512, 2)
void gemm_ce_partials(const unsigned char* __restrict__ xq,   // [B_,D_] fp8
                      const unsigned char* __restrict__ Lq,   // [V_,D_] fp8 (x2^6)
                      const int* __restrict__ targ,           // [B_]
                      float2* __restrict__ partials,          // [B_][NCHUNK]
                      float* __restrict__ gathered) {         // [B_] logit@target
    __shared__ __align__(16) unsigned char As[2][BM * BKB];   // 2 x 32 KB
    __shared__ __align__(16) unsigned char Bs[2][BN * BKB];   // 2 x 32 KB

    const int tid    = threadIdx.x;
    const int lane   = tid & 63;
    const int wid    = tid >> 6;         // 0..7
    const int wave_m = wid >> 2;         // 0..1  (row half: 128 rows)
    const int wave_n = wid & 3;          // 0..3  (col quarter: 64 cols)
    const int quad   = lane >> 4;        // 0..3
    const int l16    = lane & 15;
    const int swz    = l16 & 7;          // read-side XOR key (row&7 == l16&7)

    const int m0 = blockIdx.x * BM;      // row-block: FAST dim
    const int n0 = blockIdx.y * BN;      // col-block: SLOW dim

    // staging geometry: pass p (p=0..3) covers rows p*64..p*64+63 of the tile.
    // row = p*64 + (tid>>3); chunk pos pc = tid&7; global chunk c = pc^(row&7)
    // -- p-invariant since 64 % 8 == 0. Linear in p: src += p*64*D_, dst += p*8K.
    const int r0 = tid >> 3;
    const int c0 = (tid & 7) ^ (r0 & 7);
    const unsigned char* sA = xq + (size_t)(m0 + r0) * D_ + c0 * 16;
    const unsigned char* sB = Lq + (size_t)(n0 + r0) * D_ + c0 * 16;
    const int d0 = tid * 16;
#define STEP (64 * D_)       // global row stride per pass
#define DSTEP 8192           // LDS byte stride per pass

    f32x4 acc[8][4];
#pragma unroll
    for (int i = 0; i < 8; ++i)
#pragma unroll
        for (int j = 0; j < 4; ++j)
            acc[i][j] = (f32x4){0.f, 0.f, 0.f, 0.f};

    // byte offsets of this lane's two 16B pieces (chunks quad and quad+4,
    // XOR-swizzled): the measured-zero-conflict read phases.
    const int p0 = ((quad ^ swz) << 4);
    const int p1 = p0 ^ 64;              // ((quad+4)^swz)<<4

    // frag-read row bases
    const int arow = (wave_m * 128 + l16) * BKB;
    const int brow = (wave_n * 64 + l16) * BKB;
#define AB(mi) (arow + (mi) * (16 * BKB))
#define BB(ni) (brow + (ni) * (16 * BKB))
#define MM(A, B, MI, NI)                                                     \
    acc[MI][NI] = __builtin_amdgcn_mfma_scale_f32_16x16x128_f8f6f4(          \
        A, B, acc[MI][NI], 0, 0, 0, SCALE_A, 0, SCALE_B)

    // ---- prologue: stage K-tile 0 into buffer 0, full drain once ----------
#pragma unroll
    for (int p = 0; p < 4; ++p) {
        load_lds16(sA + (size_t)p * STEP, &As[0][d0 + p * DSTEP]);
        load_lds16(sB + (size_t)p * STEP, &Bs[0][d0 + p * DSTEP]);
    }
    asm volatile("s_waitcnt vmcnt(0)" ::: "memory");
    __builtin_amdgcn_s_barrier();

    for (int kt = 0; kt < NT; ++kt) {
        const int cur = kt & 1;
        const int nxt = cur ^ 1;
        const size_t k1 = (size_t)(kt + 1) * BKB;    // prefetch k-offset
        const bool pf = (kt + 1 < NT);
        const unsigned char* Ac = As[cur];
        const unsigned char* Bc = Bs[cur];

        int8v a0, a1, a2, a3, b0, b1, b2, b3, s;

        // ===== P1: 12 reads (P1's 6 + P2's 6); stage B-h1; 2 MFMA ==========
        a0 = frag(Ac, AB(0), p0, p1);
        a1 = frag(Ac, AB(1), p0, p1);
        b0 = frag(Bc, BB(0), p0, p1);
        a2 = frag(Ac, AB(2), p0, p1);
        a3 = frag(Ac, AB(3), p0, p1);
        b1 = frag(Bc, BB(1), p0, p1);
        if (pf) {
            load_lds16(sB + k1, &Bs[nxt][d0]);
            load_lds16(sB + k1 + (size_t)STEP, &Bs[nxt][d0 + DSTEP]);
        }
        __builtin_amdgcn_s_barrier();
        __builtin_amdgcn_s_setprio(1);
        MM(a0, b0, 0, 0); MM(a1, b0, 1, 0);
        __builtin_amdgcn_s_setprio(0);

        // ===== P2: 6 reads (P3/P4 operands); stage B-h2; 6 MFMA ============
        b2 = frag(Bc, BB(2), p0, p1);
        b3 = frag(Bc, BB(3), p0, p1);
        s  = frag(Ac, AB(4), p0, p1);
        if (pf) {
            load_lds16(sB + k1 + (size_t)2 * STEP, &Bs[nxt][d0 + 2 * DSTEP]);
            load_lds16(sB + k1 + (size_t)3 * STEP, &Bs[nxt][d0 + 3 * DSTEP]);
        }
        __builtin_amdgcn_s_barrier();
        __builtin_amdgcn_s_setprio(1);
        MM(a2, b0, 2, 0); MM(a3, b0, 3, 0);
        MM(a0, b1, 0, 1); MM(a1, b1, 1, 1); MM(a2, b1, 2, 1); MM(a3, b1, 3, 1);
        __builtin_amdgcn_s_setprio(0);

        // ===== P3: no reads (pipe drains P2's); stage A-h1; 8 MFMA =========
        if (pf) {
            load_lds16(sA + k1, &As[nxt][d0]);
            load_lds16(sA + k1 + (size_t)STEP, &As[nxt][d0 + DSTEP]);
        }
        __builtin_amdgcn_s_barrier();
        __builtin_amdgcn_s_setprio(1);
        MM(a0, b2, 0, 2); MM(a1, b2, 1, 2); MM(a2, b2, 2, 2); MM(a3, b2, 3, 2);
        MM(a0, b3, 0, 3); MM(a1, b3, 1, 3); MM(a2, b3, 2, 3); MM(a3, b3, 3, 3);
        __builtin_amdgcn_s_setprio(0);

        // ===== P4: A5-7 reload (drains under s-MFMAs); stage A-h2; 16 MFMA =
        a0 = frag(Ac, AB(5), p0, p1);    // safe: old a0-2 last used in P3
        a1 = frag(Ac, AB(6), p0, p1);
        a2 = frag(Ac, AB(7), p0, p1);
        if (pf) {
            load_lds16(sA + k1 + (size_t)2 * STEP, &As[nxt][d0 + 2 * DSTEP]);
            load_lds16(sA + k1 + (size_t)3 * STEP, &As[nxt][d0 + 3 * DSTEP]);
        }
        __builtin_amdgcn_s_barrier();
        __builtin_amdgcn_s_setprio(1);
        MM(s, b0, 4, 0); MM(s, b1, 4, 1); MM(s, b2, 4, 2); MM(s, b3, 4, 3);
        MM(a0, b0, 5, 0); MM(a0, b1, 5, 1); MM(a0, b2, 5, 2); MM(a0, b3, 5, 3);
        MM(a1, b0, 6, 0); MM(a1, b1, 6, 1); MM(a1, b2, 6, 2); MM(a1, b3, 6, 3);
        MM(a2, b0, 7, 0); MM(a2, b1, 7, 1); MM(a2, b2, 7, 2); MM(a2, b3, 7, 3);
        __builtin_amdgcn_s_setprio(0);
        asm volatile("s_waitcnt vmcnt(0)" ::: "memory");
        __builtin_amdgcn_s_barrier();
    }

    // Epilogue. C layout (16x16): col = lane&15, row = quad*4 + reg.
    // Per wave: 128 rows (wave_m half, mi 0..7) x 64 cols (wave_n quarter).
    const int row_base = m0 + wave_m * 128;
    const int col_base = n0 + wave_n * 64;
    const int chunk    = blockIdx.y * 4 + wave_n;   // 0..499

    // hoist targ loads (latency overlaps the max/exp work below)
    int tv[32];
#pragma unroll
    for (int mi = 0; mi < 8; ++mi)
#pragma unroll
        for (int r = 0; r < 4; ++r)
            tv[mi * 4 + r] = targ[row_base + mi * 16 + quad * 4 + r];

    // wave-wide max M (valid shift for all 128 rows of this wave tile)
    float M = acc[0][0][0];
#pragma unroll
    for (int mi = 0; mi < 8; ++mi)
#pragma unroll
        for (int ni = 0; ni < 4; ++ni)
#pragma unroll
            for (int r = 0; r < 4; ++r)
                M = fmaxf(M, acc[mi][ni][r]);
#pragma unroll
    for (int off = 1; off < 64; off <<= 1)
        M = fmaxf(M, __shfl_xor(M, off, 64));

    // all exps first (independent), then flat shuffle rounds (32-way ILP)
    float sv[32];
#pragma unroll
    for (int mi = 0; mi < 8; ++mi)
#pragma unroll
        for (int r = 0; r < 4; ++r)
            sv[mi * 4 + r] = __expf(acc[mi][0][r] - M) + __expf(acc[mi][1][r] - M) +
                             __expf(acc[mi][2][r] - M) + __expf(acc[mi][3][r] - M);
#pragma unroll
    for (int off = 1; off < 16; off <<= 1)
#pragma unroll
        for (int i = 0; i < 32; ++i)
            sv[i] += __shfl_xor(sv[i], off, 64);

    if (l16 == 0) {
#pragma unroll
        for (int mi = 0; mi < 8; ++mi)
#pragma unroll
            for (int r = 0; r < 4; ++r) {
                int row = row_base + mi * 16 + quad * 4 + r;
                partials[(size_t)row * NCHUNK + chunk] = make_float2(M, sv[mi * 4 + r]);
            }
    }

    // target gather (rare hit: ~4096/32000 of (row, col-block) pairs)
#pragma unroll
    for (int mi = 0; mi < 8; ++mi)
#pragma unroll
        for (int r = 0; r < 4; ++r) {
            int row = row_base + mi * 16 + quad * 4 + r;
            int cb  = col_base + l16;
            int t   = tv[mi * 4 + r];
            if (cb      == t) gathered[row] = acc[mi][0][r];
            if (cb + 16 == t) gathered[row] = acc[mi][1][r];
            if (cb + 32 == t) gathered[row] = acc[mi][2][r];
            if (cb + 48 == t) gathered[row] = acc[mi][3][r];
        }
}

// ------------------------------------------------------ per-row combine -----
// one wave per row; block 256 -> 4 rows/block; grid B_/4
__global__ void combine_rows(const float2* __restrict__ partials,
                             const float* __restrict__ gathered,
                             const int* __restrict__ targ,
                             const float* __restrict__ cw,
                             float* __restrict__ row_loss,
                             float* __restrict__ row_w) {
    int row  = blockIdx.x * 4 + (threadIdx.x >> 6);
    int lane = threadIdx.x & 63;
    float m = -3.0e38f, s = 0.f;
    for (int c = lane; c < NCHUNK; c += 64) {
        float2 p = partials[(size_t)row * NCHUNK + c];
        float nm = fmaxf(m, p.x);
        s = s * __expf(m - nm) + p.y * __expf(p.x - nm);
        m = nm;
    }
#pragma unroll
    for (int off = 32; off; off >>= 1) {
        float om = __shfl_xor(m, off, 64);
        float os = __shfl_xor(s, off, 64);
        float nm = fmaxf(m, om);
        s = s * __expf(m - nm) + os * __expf(om - nm);
        m = nm;
    }
    if (lane == 0) {
        float logZ = m + __logf(s);
        int t = targ[row];
        bool valid = (t != -100);
        int ts = valid ? t : 0;
        float w = valid ? cw[ts] : 0.f;
        row_loss[row] = w * (logZ - gathered[row]);
        row_w[row]    = w;
    }
}

// ---------------------------------------------------------- final reduce ----
__global__ void final_reduce(const float* __restrict__ rl,
                             const float* __restrict__ rw,
                             float* __restrict__ out) {
    __shared__ float sl[4], sw[4];
    float a = 0.f, b = 0.f;
    for (int i = threadIdx.x; i < B_; i += 256) { a += rl[i]; b += rw[i]; }
#pragma unroll
    for (int off = 32; off; off >>= 1) {
        a += __shfl_xor(a, off, 64);
        b += __shfl_xor(b, off, 64);
    }
    int w = threadIdx.x >> 6;
    if ((threadIdx.x & 63) == 0) { sl[w] = a; sw[w] = b; }
    __syncthreads();
    if (threadIdx.x == 0) {
        float ta = sl[0] + sl[1] + sl[2] + sl[3];
        float tb = sw[0] + sw[1] + sw[2] + sw[3];
        out[0] = ta / tb;
    }
}

// ------------------------------------------------------------------ launch --
extern "C" void kernel_launch(void* const* d_in, const int* in_sizes, int n_in,
                              void* d_out, int out_size, void* d_ws, size_t ws_size,
                              hipStream_t stream) {
    const float* x  = (const float*)d_in[0];   // [B_,D_]
    const float* L  = (const float*)d_in[1];   // [V_,D_]
    const int* targ = (const int*)d_in[2];     // [B_]
    const float* cw = (const float*)d_in[3];   // [V_]
    float* out = (float*)d_out;

    // workspace carve-up (all 256B-aligned)
    char* ws = (char*)d_ws;
    size_t o = 0;
    unsigned char* xq = (unsigned char*)(ws + o);  o += (size_t)B_ * D_;         // 8.4 MB
    unsigned char* Lq = (unsigned char*)(ws + o);  o += (size_t)V_ * D_;         // 65.5 MB
    float2* partials = (float2*)(ws + o);          o += (size_t)B_ * NCHUNK * 8; // 16.4 MB
    float* gathered = (float*)(ws + o);            o += (size_t)B_ * 4;
    float* row_loss = (float*)(ws + o);            o += (size_t)B_ * 4;
    float* row_w    = (float*)(ws + o);            o += (size_t)B_ * 4;
    (void)ws_size;

    // 1) fused cast (x as-is; L pre-scaled 2^6, undone by MFMA e8m0 scale 2^-6)
    {
        int n4 = (B_ * D_) / 4 + (V_ * D_) / 4;
        cast_f32_to_fp8<<<(n4 + 255) / 256, 256, 0, stream>>>(
            x, L, (unsigned*)xq, (unsigned*)Lq);
    }

    // 2) fused MX-fp8 GEMM + per-tile online softmax partials
    {
        dim3 grid(B_ / BM, V_ / BN);   // (16 fast, 125 slow) -- L2 locality
        gemm_ce_partials<<<grid, 512, 0, stream>>>(xq, Lq, targ, partials, gathered);
    }

    // 3) per-row combine
    combine_rows<<<B_ / 4, 256, 0, stream>>>(partials, gathered, targ, cw, row_loss, row_w);

    // 4) final scalar
    final_reduce<<<1, 256, 0, stream>>>(row_loss, row_w, out);
}